// Round 5
// baseline (683.352 us; speedup 1.0000x reference)
//
#include <hip/hip_runtime.h>
#include <hip/hip_bf16.h>

#define NODES 50000
#define EDGES 800000
#define DIN   19
#define LAYERS 3
#define BN_EPS 1e-5f

#define NBINS 196          // ceil(NODES/256), bin = dst>>8
#define EPB   2048         // edges per sort chunk
#define NBLK  391          // ceil(EDGES/EPB)
#define NTILES 782         // ceil(NODES/64)
#define GRID  782          // == NTILES; 4 blocks/CU capacity => fully resident
#define TPB   256

typedef __attribute__((ext_vector_type(4))) float f32x4;
typedef __attribute__((ext_vector_type(8))) short s16x8;

__device__ inline ushort bf16bits(float f) {
    __hip_bfloat16 h = __float2bfloat16(f);
    return *reinterpret_cast<ushort*>(&h);
}
__device__ inline float bf16lo(unsigned v) { return __uint_as_float(v << 16); }
__device__ inline float bf16hi(unsigned v) { return __uint_as_float(v & 0xFFFF0000u); }

union SMem {
    struct { int hist[256], cur[256], wsum[4]; unsigned stage[EPB]; } sort;
    struct { int red[256]; int segoff[NBLK], segcnt[NBLK], pre[NBLK + 1];
             int deg[256], loff[256], cur[256], wsum[4]; } binb;
    struct { ushort aggtile[64][136]; float red[4][128]; } gemm;   // 19.5 KB max
};

// ---------------- grid barrier (monotonic, zeroed each call by k_first) ----------------
// barr[0..127]: 8 arrival counters at stride 16; barr[128]: go word.
__device__ inline void gbar(int* barr, int k) {
    __syncthreads();
    if (threadIdx.x == 0) {
        __threadfence();   // release: flush this XCD's writes
        __hip_atomic_fetch_add(&barr[(blockIdx.x & 7) * 16], 1,
                               __ATOMIC_RELEASE, __HIP_MEMORY_SCOPE_AGENT);
        if (blockIdx.x == 0) {
            const int target = (k + 1) * GRID;
            for (;;) {
                int s = 0;
                #pragma unroll
                for (int i = 0; i < 8; ++i)
                    s += __hip_atomic_load(&barr[i * 16], __ATOMIC_RELAXED, __HIP_MEMORY_SCOPE_AGENT);
                if (s >= target) break;
                __builtin_amdgcn_s_sleep(4);
            }
            __hip_atomic_fetch_add(&barr[128], 1, __ATOMIC_RELEASE, __HIP_MEMORY_SCOPE_AGENT);
        } else {
            while (__hip_atomic_load(&barr[128], __ATOMIC_RELAXED, __HIP_MEMORY_SCOPE_AGENT) < k + 1)
                __builtin_amdgcn_s_sleep(16);
        }
        __threadfence();   // acquire: invalidate stale lines
    }
    __syncthreads();
}

// ---------------- phase: per-chunk LDS counting sort of edges by dst>>8 ----------------

__device__ inline void do_sort(int c, int t, const int* __restrict__ esrc,
                               const int* __restrict__ edst, int2* __restrict__ cb,
                               int* __restrict__ bintot, unsigned* __restrict__ bbuf, SMem& sm) {
    int ln = t & 63, wv = t >> 6;
    int e0 = c * EPB;
    int ne = min(EPB, EDGES - e0);
    int d[8]; unsigned pk[8];
    #pragma unroll
    for (int i = 0; i < 8; ++i) {
        int j = t + i * TPB;
        if (j < ne) {
            int dd = edst[e0 + j];
            d[i] = dd;
            pk[i] = ((unsigned)(dd & 255) << 24) | (unsigned)esrc[e0 + j];
        } else d[i] = -1;
    }
    sm.sort.hist[t] = 0;
    __syncthreads();
    #pragma unroll
    for (int i = 0; i < 8; ++i)
        if (d[i] >= 0) atomicAdd(&sm.sort.hist[d[i] >> 8], 1);
    __syncthreads();
    int cnt = sm.sort.hist[t], inc = cnt;
    #pragma unroll
    for (int s = 1; s < 64; s <<= 1) {
        int u = __shfl_up(inc, s);
        if (ln >= s) inc += u;
    }
    if (ln == 63) sm.sort.wsum[wv] = inc;
    __syncthreads();
    int woff = 0;
    #pragma unroll
    for (int i = 0; i < 4; ++i) if (i < wv) woff += sm.sort.wsum[i];
    int excl = woff + inc - cnt;
    sm.sort.cur[t] = excl;
    if (t < NBINS) {
        cb[t * NBLK + c] = make_int2(excl, cnt);
        if (cnt) atomicAdd(&bintot[t], cnt);
    }
    __syncthreads();
    #pragma unroll
    for (int i = 0; i < 8; ++i)
        if (d[i] >= 0) {
            int slot = atomicAdd(&sm.sort.cur[d[i] >> 8], 1);
            sm.sort.stage[slot] = pk[i];
        }
    __syncthreads();
    #pragma unroll
    for (int i = 0; i < 8; ++i) {
        int j = t + i * TPB;
        if (j < ne) bbuf[e0 + j] = sm.sort.stage[j];
    }
    __syncthreads();
}

// ---------------- phase: per-bin CSR assembly (flattened edge iteration) ----------------

__device__ inline int ubound(const int* pre, int f) {
    int lo = 0, hi = NBLK;
    while (lo + 1 < hi) {
        int mid = (lo + hi) >> 1;
        if (pre[mid] <= f) lo = mid; else hi = mid;
    }
    return lo;
}

__device__ inline void do_binb(int b, int t, const int2* __restrict__ cb,
                               const int* __restrict__ bintot, const unsigned* __restrict__ bbuf,
                               int* __restrict__ off, float* __restrict__ rden,
                               int* __restrict__ ebuf, SMem& sm) {
    int ln = t & 63, wv = t >> 6;
    sm.binb.red[t] = (t < b) ? bintot[t] : 0;
    __syncthreads();
    #pragma unroll
    for (int s = 128; s > 0; s >>= 1) {
        if (t < s) sm.binb.red[t] += sm.binb.red[t + s];
        __syncthreads();
    }
    int binoff = sm.binb.red[0];
    for (int sg = t; sg < NBLK; sg += TPB) {
        int2 c = cb[b * NBLK + sg];
        sm.binb.segoff[sg] = c.x;
        sm.binb.segcnt[sg] = c.y;
    }
    sm.binb.deg[t] = 0;
    sm.binb.cur[t] = 0;
    __syncthreads();
    if (wv == 0) {                      // wave 0: prefix over 391 segment counts
        int carry = 0;
        for (int base = 0; base < NBLK; base += 64) {
            int idx = base + ln;
            int v = (idx < NBLK) ? sm.binb.segcnt[idx] : 0;
            int inc = v;
            #pragma unroll
            for (int s = 1; s < 64; s <<= 1) {
                int u = __shfl_up(inc, s);
                if (ln >= s) inc += u;
            }
            if (idx < NBLK) sm.binb.pre[idx] = carry + inc - v;
            carry += __shfl(inc, 63);
        }
        if (ln == 0) sm.binb.pre[NBLK] = carry;
    }
    __syncthreads();
    int total = sm.binb.pre[NBLK];
    for (int f = t; f < total; f += TPB) {
        int sg = ubound(sm.binb.pre, f);
        unsigned e = bbuf[sg * EPB + sm.binb.segoff[sg] + (f - sm.binb.pre[sg])];
        atomicAdd(&sm.binb.deg[e >> 24], 1);
    }
    __syncthreads();
    int dv = sm.binb.deg[t], inc2 = dv;
    #pragma unroll
    for (int s = 1; s < 64; s <<= 1) {
        int u = __shfl_up(inc2, s);
        if (ln >= s) inc2 += u;
    }
    if (ln == 63) sm.binb.wsum[wv] = inc2;
    __syncthreads();
    int woff = 0;
    #pragma unroll
    for (int i = 0; i < 4; ++i) if (i < wv) woff += sm.binb.wsum[i];
    int excl = woff + inc2 - dv;
    sm.binb.loff[t] = excl;
    int node = (b << 8) + t;
    if (node < NODES) {
        off[node] = binoff + excl;
        rden[node] = 1.0f / fmaxf((float)dv, 1.0f);
    }
    if (b == NBINS - 1 && t == 0) off[NODES] = EDGES;
    __syncthreads();
    for (int f = t; f < total; f += TPB) {
        int sg = ubound(sm.binb.pre, f);
        unsigned e = bbuf[sg * EPB + sm.binb.segoff[sg] + (f - sm.binb.pre[sg])];
        int dd = e >> 24;
        int slot = atomicAdd(&sm.binb.cur[dd], 1);
        ebuf[binoff + sm.binb.loff[dd] + slot] = (int)(e & 0xFFFFFFu);
    }
    __syncthreads();
}

// ---------------- phase: mean-aggregate 64 rows into LDS tile ----------------

__device__ inline void do_agg(int rb, int t, const int* __restrict__ off,
                              const int* __restrict__ ebuf, const float* __restrict__ rden,
                              const ushort* __restrict__ hb, SMem& sm) {
    const unsigned* HB = (const unsigned*)hb;            // 32 uints per row
    unsigned (*AG)[68] = (unsigned (*)[68])sm.gemm.aggtile;
    int lane = t & 63, wave = t >> 6;
    int half = lane >> 5, fl = lane & 31;
    #pragma unroll 1
    for (int i = 0; i < 16; ++i) {
        int n = rb * 64 + wave * 16 + i;
        if (n < NODES) {
            int p0 = off[n], p1 = off[n + 1];
            float a0 = 0.0f, a1 = 0.0f;
            int p = p0 + half;
            for (; p + 6 < p1; p += 8) {
                int s0 = ebuf[p], s1 = ebuf[p + 2], s2 = ebuf[p + 4], s3 = ebuf[p + 6];
                unsigned v0 = HB[(size_t)s0 * 32 + fl];
                unsigned v1 = HB[(size_t)s1 * 32 + fl];
                unsigned v2 = HB[(size_t)s2 * 32 + fl];
                unsigned v3 = HB[(size_t)s3 * 32 + fl];
                a0 += bf16lo(v0); a1 += bf16hi(v0);
                a0 += bf16lo(v1); a1 += bf16hi(v1);
                a0 += bf16lo(v2); a1 += bf16hi(v2);
                a0 += bf16lo(v3); a1 += bf16hi(v3);
            }
            for (; p < p1; p += 2) {
                unsigned v = HB[(size_t)ebuf[p] * 32 + fl];
                a0 += bf16lo(v); a1 += bf16hi(v);
            }
            a0 += __shfl_xor(a0, 32);
            a1 += __shfl_xor(a1, 32);
            if (half == 0) {
                float rd = rden[n];
                AG[wave * 16 + i][fl] =
                    (unsigned)bf16bits(a0 * rd) | ((unsigned)bf16bits(a1 * rd) << 16);
            }
        }
    }
    __syncthreads();
}

// ---------------- phase: 64-row GEMM tile + fused BN stats ----------------
// ALDS: A = [LDS aggtile (k<64) | global hb (k>=64)]; else A = Aglob (lda 32)

template<int K, bool ALDS>
__device__ inline void do_gemm(int rb, int t, const ushort* __restrict__ Aglob,
                               const ushort* __restrict__ WT, const float* __restrict__ bias,
                               ushort* __restrict__ tb, float* __restrict__ stats,
                               const ushort* __restrict__ hb, SMem& sm) {
    int lane = t & 63, wave = t >> 6;
    int row0 = rb * 64 + wave * 16;
    int r = lane & 15, g = lane >> 4;
    f32x4 acc[4] = {{0.f,0.f,0.f,0.f},{0.f,0.f,0.f,0.f},{0.f,0.f,0.f,0.f},{0.f,0.f,0.f,0.f}};
    int ar = row0 + r;
    if (ar >= NODES) ar = NODES - 1;
    #pragma unroll
    for (int k0 = 0; k0 < K; k0 += 32) {
        s16x8 af;
        if (ALDS) {
            if (k0 < 64) af = *(const s16x8*)&sm.gemm.aggtile[wave * 16 + r][k0 + g * 8];
            else         af = *(const s16x8*)(hb + (size_t)ar * 64 + (k0 - 64) + g * 8);
        } else {
            af = *(const s16x8*)(Aglob + (size_t)ar * 32 + k0 + g * 8);
        }
        #pragma unroll
        for (int j = 0; j < 4; ++j) {
            s16x8 bf = *(const s16x8*)(WT + (size_t)(j * 16 + r) * K + k0 + g * 8);
            acc[j] = __builtin_amdgcn_mfma_f32_16x16x32_bf16(af, bf, acc[j], 0, 0, 0);
        }
    }
    float s_[4], q_[4];
    #pragma unroll
    for (int j = 0; j < 4; ++j) {
        float b = bias[j * 16 + r];
        float s = 0.0f, q = 0.0f;
        #pragma unroll
        for (int i = 0; i < 4; ++i) {
            int row = row0 + g * 4 + i;
            if (row < NODES) {
                float v = acc[j][i] + b;
                tb[(size_t)row * 64 + j * 16 + r] = bf16bits(v);
                s += v; q += v * v;
            }
        }
        s += __shfl_xor(s, 16); s += __shfl_xor(s, 32);
        q += __shfl_xor(q, 16); q += __shfl_xor(q, 32);
        s_[j] = s; q_[j] = q;
    }
    if (g == 0) {
        #pragma unroll
        for (int j = 0; j < 4; ++j) {
            sm.gemm.red[wave][j * 16 + r] = s_[j];
            sm.gemm.red[wave][64 + j * 16 + r] = q_[j];
        }
    }
    __syncthreads();
    if (t < 128) {
        float tot = sm.gemm.red[0][t] + sm.gemm.red[1][t] +
                    sm.gemm.red[2][t] + sm.gemm.red[3][t];
        atomicAdd(&stats[t * 16], tot);
    }
    __syncthreads();
}

// ---------------- phase: BN finalize + ReLU (+residual) ----------------

__device__ inline void do_apply(int t, const ushort* __restrict__ tb,
                                const float* __restrict__ stats, const float* __restrict__ gamma,
                                const float* __restrict__ beta, float* __restrict__ h,
                                ushort* __restrict__ hb, bool residual) {
    const float invN = 1.0f / NODES;
    for (int idx = blockIdx.x * TPB + t; idx < NODES * 16; idx += GRID * TPB) {
        int n = idx >> 4;
        int j = (idx & 15) * 4;
        ushort4 tv = *(const ushort4*)(tb + (size_t)n * 64 + j);
        float tf[4] = { __uint_as_float((unsigned)tv.x << 16), __uint_as_float((unsigned)tv.y << 16),
                        __uint_as_float((unsigned)tv.z << 16), __uint_as_float((unsigned)tv.w << 16) };
        f32x4 hv;
        if (residual) hv = *(const f32x4*)(h + (size_t)n * 64 + j);
        float out[4];
        ushort ub[4];
        #pragma unroll
        for (int k = 0; k < 4; ++k) {
            int f = j + k;
            float mu = stats[f * 16] * invN;
            float var = stats[(64 + f) * 16] * invN - mu * mu;
            float sc = gamma[f] * rsqrtf(var + BN_EPS);
            float sh = beta[f] - mu * sc;
            float v = fmaxf(tf[k] * sc + sh, 0.0f);
            out[k] = residual ? (hv[k] + v) : v;
            ub[k] = bf16bits(out[k]);
        }
        *(f32x4*)(h + (size_t)n * 64 + j) = f32x4{out[0], out[1], out[2], out[3]};
        *(ushort4*)(hb + (size_t)n * 64 + j) = make_ushort4(ub[0], ub[1], ub[2], ub[3]);
    }
}

// ---------------- k_first: zero barriers/stats + weight & input prep ----------------

__global__ void k_first(const float* __restrict__ x, const float* __restrict__ w_in,
                        const float* __restrict__ wl, const float* __restrict__ wr,
                        ushort* __restrict__ xpad, ushort* __restrict__ WiT,
                        ushort* __restrict__ WcatT, int* __restrict__ barr,
                        int* __restrict__ bintot, float* __restrict__ stats) {
    int i0 = blockIdx.x * blockDim.x + threadIdx.x;
    int stride = gridDim.x * blockDim.x;
    for (int i = i0; i < 256; i += stride) barr[i] = 0;
    for (int i = i0; i < NBINS; i += stride) bintot[i] = 0;
    for (int i = i0; i < 4 * 2048; i += stride) stats[i] = 0.0f;
    for (int i = i0; i < 64 * 32; i += stride) {
        int c = i >> 5, k = i & 31;
        WiT[i] = bf16bits(k < DIN ? w_in[k * 64 + c] : 0.0f);
    }
    for (int i = i0; i < LAYERS * 64 * 128; i += stride) {
        int l = i >> 13, rem = i & 8191;
        int c = rem >> 7, k = rem & 127;
        float v = (k < 64) ? wl[(l * 64 + k) * 64 + c] : wr[(l * 64 + (k - 64)) * 64 + c];
        WcatT[i] = bf16bits(v);
    }
    for (int i = i0; i < NODES * 32; i += stride) {
        int n = i >> 5, k = i & 31;
        xpad[i] = bf16bits(k < DIN ? x[n * DIN + k] : 0.0f);
    }
}

// ---------------- the mega kernel ----------------

__global__ __launch_bounds__(TPB, 4) void k_mega(
    const int* __restrict__ esrc, const int* __restrict__ edst,
    const float* __restrict__ b_in, const float* __restrict__ bn0g, const float* __restrict__ bn0b,
    const float* __restrict__ bl, const float* __restrict__ bng, const float* __restrict__ bnb,
    const ushort* __restrict__ xpad, const ushort* __restrict__ WiT, const ushort* __restrict__ WcatT,
    int2* __restrict__ cb, int* __restrict__ bintot, unsigned* __restrict__ bbuf,
    int* __restrict__ off, float* __restrict__ rden, int* __restrict__ ebuf,
    ushort* __restrict__ tb, ushort* __restrict__ hb, float* __restrict__ stats,
    float* __restrict__ h, int* __restrict__ barr) {
    __shared__ SMem sm;
    int t = threadIdx.x;
    int bk = 0;

    // P0: counting sort of edges into bins
    for (int c = blockIdx.x; c < NBLK; c += GRID)
        do_sort(c, t, esrc, edst, cb, bintot, bbuf, sm);
    gbar(barr, bk++);

    // P1: CSR assembly (196 blocks) + input-proj GEMM (all blocks)
    if (blockIdx.x < NBINS)
        do_binb(blockIdx.x, t, cb, bintot, bbuf, off, rden, ebuf, sm);
    __syncthreads();
    do_gemm<32, false>(blockIdx.x, t, xpad, WiT, b_in, tb, stats, nullptr, sm);
    gbar(barr, bk++);

    // P2: BN+ReLU
    do_apply(t, tb, stats, bn0g, bn0b, h, hb, false);
    gbar(barr, bk++);

    for (int l = 0; l < LAYERS; ++l) {
        // P: aggregate 64 rows -> LDS, then GEMM [agg|h] @ Wcat
        do_agg(blockIdx.x, t, off, ebuf, rden, hb, sm);
        do_gemm<128, true>(blockIdx.x, t, nullptr, WcatT + l * 8192, bl + l * 64,
                           tb, stats + (l + 1) * 2048, hb, sm);
        gbar(barr, bk++);
        // P: BN+ReLU+residual
        do_apply(t, tb, stats + (l + 1) * 2048, bng + l * 64, bnb + l * 64, h, hb, true);
        if (l < LAYERS - 1) gbar(barr, bk++);
    }
}

// ---------------- launch ----------------

extern "C" void kernel_launch(void* const* d_in, const int* in_sizes, int n_in,
                              void* d_out, int out_size, void* d_ws, size_t ws_size,
                              hipStream_t stream) {
    const float* x    = (const float*)d_in[0];
    const int*   ei   = (const int*)d_in[1];
    const float* w_in = (const float*)d_in[2];
    const float* b_in = (const float*)d_in[3];
    const float* bn0g = (const float*)d_in[4];
    const float* bn0b = (const float*)d_in[5];
    const float* wl   = (const float*)d_in[6];
    const float* bl   = (const float*)d_in[7];
    const float* wr   = (const float*)d_in[8];
    const float* bng  = (const float*)d_in[9];
    const float* bnb  = (const float*)d_in[10];
    const int* esrc = ei;
    const int* edst = ei + EDGES;
    float* h = (float*)d_out;

    char* p = (char*)d_ws;
    auto alloc = [&](size_t bytes) {
        char* r = p;
        p += (bytes + 255) & ~size_t(255);
        return r;
    };
    int*      barr   = (int*)alloc(1024);
    int*      bintot = (int*)alloc((size_t)NBINS * 4);
    float*    stats  = (float*)alloc((size_t)4 * 2048 * 4);
    int2*     cb     = (int2*)alloc((size_t)NBINS * NBLK * 8);
    unsigned* bbuf   = (unsigned*)alloc((size_t)NBLK * EPB * 4);
    int*      off    = (int*)alloc((size_t)(NODES + 1) * 4);
    float*    rden   = (float*)alloc((size_t)NODES * 4);
    int*      ebuf   = (int*)alloc((size_t)EDGES * 4);
    ushort*   xpad   = (ushort*)alloc((size_t)NODES * 32 * 2);
    ushort*   WiT    = (ushort*)alloc(64 * 32 * 2);
    ushort*   WcatT  = (ushort*)alloc(LAYERS * 64 * 128 * 2);
    ushort*   tb     = (ushort*)alloc((size_t)NODES * 64 * 2);
    ushort*   hb     = (ushort*)alloc((size_t)NODES * 64 * 2);

    k_first<<<512, TPB, 0, stream>>>(x, w_in, wl, wr, xpad, WiT, WcatT, barr, bintot, stats);
    k_mega<<<GRID, TPB, 0, stream>>>(esrc, edst, b_in, bn0g, bn0b, bl, bng, bnb,
                                     xpad, WiT, WcatT, cb, bintot, bbuf, off, rden, ebuf,
                                     tb, hb, stats, h, barr);
}

// Round 6
// 360.780 us; speedup vs baseline: 1.8941x; 1.8941x over previous
//
#include <hip/hip_runtime.h>
#include <hip/hip_bf16.h>

#define NODES 50000
#define EDGES 800000
#define DIN   19
#define LAYERS 3
#define BN_EPS 1e-5f

#define NBINS 196          // ceil(NODES/256), bin = dst>>8
#define EPB   4096         // edges per sort chunk
#define NBLK  196          // ceil(EDGES/EPB)
#define NTILES 782         // ceil(NODES/64)
#define TPB   256

typedef __attribute__((ext_vector_type(4))) float f32x4;
typedef __attribute__((ext_vector_type(8))) short s16x8;

__device__ inline ushort bf16bits(float f) {
    __hip_bfloat16 h = __float2bfloat16(f);
    return *reinterpret_cast<ushort*>(&h);
}
__device__ inline float bf16lo(unsigned v) { return __uint_as_float(v << 16); }
__device__ inline float bf16hi(unsigned v) { return __uint_as_float(v & 0xFFFF0000u); }

// ---------------- prep: zero counters/stats, build transposed bf16 weights ----------------

__global__ void k_wprep(const float* __restrict__ w_in, const float* __restrict__ wl,
                        const float* __restrict__ wr, ushort* __restrict__ WiT,
                        ushort* __restrict__ WcatT, int* __restrict__ bintot,
                        float* __restrict__ stats) {
    int i0 = blockIdx.x * blockDim.x + threadIdx.x;
    int stride = gridDim.x * blockDim.x;
    for (int i = i0; i < NBINS; i += stride) bintot[i] = 0;
    for (int i = i0; i < 4 * 2048; i += stride) stats[i] = 0.0f;
    for (int i = i0; i < 64 * 32; i += stride) {
        int c = i >> 5, k = i & 31;
        WiT[i] = bf16bits(k < DIN ? w_in[k * 64 + c] : 0.0f);
    }
    for (int i = i0; i < LAYERS * 64 * 128; i += stride) {
        int l = i >> 13, rem = i & 8191;
        int c = rem >> 7, k = rem & 127;
        float v = (k < 64) ? wl[(l * 64 + k) * 64 + c] : wr[(l * 64 + (k - 64)) * 64 + c];
        WcatT[i] = bf16bits(v);
    }
}

// ---------------- pass A: per-block LDS counting sort of edges by dst>>8 ----------------

__global__ __launch_bounds__(1024) void k_sortA(const int* __restrict__ src, const int* __restrict__ dst,
                                                int2* __restrict__ cb, int* __restrict__ bintot,
                                                unsigned* __restrict__ bbuf) {
    __shared__ int hist[256];
    __shared__ int cur[256];
    __shared__ int wsum4[4];
    __shared__ unsigned stage[EPB];
    int blk = blockIdx.x, t = threadIdx.x;
    int e0 = blk * EPB;
    int ne = min(EPB, EDGES - e0);
    int d[4]; unsigned pk[4];
    #pragma unroll
    for (int i = 0; i < 4; ++i) {
        int j = t + i * 1024;
        if (j < ne) {
            int dd = dst[e0 + j];
            d[i] = dd;
            pk[i] = ((unsigned)(dd & 255) << 24) | (unsigned)src[e0 + j];
        } else d[i] = -1;
    }
    if (t < 256) hist[t] = 0;
    __syncthreads();
    #pragma unroll
    for (int i = 0; i < 4; ++i)
        if (d[i] >= 0) atomicAdd(&hist[d[i] >> 8], 1);
    __syncthreads();
    int ln = t & 63, wv = t >> 6;
    int cntv = 0, inc = 0;
    if (t < 256) {
        cntv = hist[t];
        inc = cntv;
        #pragma unroll
        for (int s = 1; s < 64; s <<= 1) {
            int u = __shfl_up(inc, s);
            if (ln >= s) inc += u;
        }
        if (ln == 63) wsum4[wv] = inc;
    }
    __syncthreads();
    if (t < 256) {
        int woff = 0;
        #pragma unroll
        for (int i = 0; i < 4; ++i) if (i < wv) woff += wsum4[i];
        int excl = woff + inc - cntv;
        cur[t] = excl;
        if (t < NBINS) {
            cb[t * NBLK + blk] = make_int2(excl, cntv);
            if (cntv) atomicAdd(&bintot[t], cntv);
        }
    }
    __syncthreads();
    #pragma unroll
    for (int i = 0; i < 4; ++i)
        if (d[i] >= 0) {
            int slot = atomicAdd(&cur[d[i] >> 8], 1);
            stage[slot] = pk[i];
        }
    __syncthreads();
    #pragma unroll
    for (int i = 0; i < 4; ++i) {
        int j = t + i * 1024;
        if (j < ne) bbuf[e0 + j] = stage[j];
    }
}

// ---------------- pass B: per-bin CSR assembly (flattened edge iteration) ----------------

__device__ inline int ubound(const int* pre, int f) {
    int lo = 0, hi = NBLK;
    while (lo + 1 < hi) {
        int mid = (lo + hi) >> 1;
        if (pre[mid] <= f) lo = mid; else hi = mid;
    }
    return lo;
}

__global__ __launch_bounds__(TPB) void k_binB(const int2* __restrict__ cb, const int* __restrict__ bintot,
                                              const unsigned* __restrict__ bbuf,
                                              int* __restrict__ off, float* __restrict__ rden,
                                              int* __restrict__ ebuf) {
    __shared__ int red[256];
    __shared__ int segoff[NBLK], segcnt[NBLK], pre[NBLK + 1];
    __shared__ int deg[256], loff[256], cur[256];
    __shared__ int wsum4[4];
    int b = blockIdx.x, t = threadIdx.x;
    int ln = t & 63, wv = t >> 6;
    red[t] = (t < b) ? bintot[t] : 0;
    __syncthreads();
    #pragma unroll
    for (int s = 128; s > 0; s >>= 1) {
        if (t < s) red[t] += red[t + s];
        __syncthreads();
    }
    int binoff = red[0];
    if (t < NBLK) {
        int2 c = cb[b * NBLK + t];
        segoff[t] = c.x; segcnt[t] = c.y;
    }
    deg[t] = 0; cur[t] = 0;
    __syncthreads();
    if (wv == 0) {                      // wave 0: prefix over NBLK segment counts
        int carry = 0;
        for (int base = 0; base < NBLK; base += 64) {
            int idx = base + ln;
            int v = (idx < NBLK) ? segcnt[idx] : 0;
            int inc = v;
            #pragma unroll
            for (int s = 1; s < 64; s <<= 1) {
                int u = __shfl_up(inc, s);
                if (ln >= s) inc += u;
            }
            if (idx < NBLK) pre[idx] = carry + inc - v;
            carry += __shfl(inc, 63);
        }
        if (ln == 0) pre[NBLK] = carry;
    }
    __syncthreads();
    int total = pre[NBLK];
    for (int f = t; f < total; f += TPB) {
        int sg = ubound(pre, f);
        unsigned e = bbuf[sg * EPB + segoff[sg] + (f - pre[sg])];
        atomicAdd(&deg[e >> 24], 1);
    }
    __syncthreads();
    int dv = deg[t], inc2 = dv;
    #pragma unroll
    for (int s = 1; s < 64; s <<= 1) {
        int u = __shfl_up(inc2, s);
        if (ln >= s) inc2 += u;
    }
    if (ln == 63) wsum4[wv] = inc2;
    __syncthreads();
    int woff = 0;
    #pragma unroll
    for (int i = 0; i < 4; ++i) if (i < wv) woff += wsum4[i];
    int excl = woff + inc2 - dv;
    loff[t] = excl;
    int node = (b << 8) + t;
    if (node < NODES) {
        off[node] = binoff + excl;
        rden[node] = 1.0f / fmaxf((float)dv, 1.0f);
    }
    if (b == NBINS - 1 && t == 0) off[NODES] = EDGES;
    __syncthreads();
    for (int f = t; f < total; f += TPB) {
        int sg = ubound(pre, f);
        unsigned e = bbuf[sg * EPB + segoff[sg] + (f - pre[sg])];
        int dd = e >> 24;
        int slot = atomicAdd(&cur[dd], 1);
        ebuf[binoff + loff[dd] + slot] = (int)(e & 0xFFFFFFu);
    }
}

// ---------------- shared GEMM epilogue: bias + bf16 store + fused BN stats ----------------

__device__ inline void gemm_epilogue(int t, int row0, f32x4* acc, const float* __restrict__ bias,
                                     ushort* __restrict__ tb, float* __restrict__ stats,
                                     float (*red)[128]) {
    int lane = t & 63, wave = t >> 6;
    int r = lane & 15, g = lane >> 4;
    float s_[4], q_[4];
    #pragma unroll
    for (int j = 0; j < 4; ++j) {
        float b = bias[j * 16 + r];
        float s = 0.0f, q = 0.0f;
        #pragma unroll
        for (int i = 0; i < 4; ++i) {
            int row = row0 + wave * 16 + g * 4 + i;
            if (row < NODES) {
                float v = acc[j][i] + b;
                tb[(size_t)row * 64 + j * 16 + r] = bf16bits(v);
                s += v; q += v * v;
            }
        }
        s += __shfl_xor(s, 16); s += __shfl_xor(s, 32);
        q += __shfl_xor(q, 16); q += __shfl_xor(q, 32);
        s_[j] = s; q_[j] = q;
    }
    if (g == 0) {
        #pragma unroll
        for (int j = 0; j < 4; ++j) {
            red[wave][j * 16 + r] = s_[j];
            red[wave][64 + j * 16 + r] = q_[j];
        }
    }
    __syncthreads();
    if (t < 128) {
        float tot = red[0][t] + red[1][t] + red[2][t] + red[3][t];
        atomicAdd(&stats[t * 16], tot);
    }
}

// ---------------- input-proj GEMM: stages x (fp32) -> bf16 LDS tile, K=32 ----------------

__global__ __launch_bounds__(TPB) void k_gemm0(const float* __restrict__ x, const ushort* __restrict__ WiT,
                                               const float* __restrict__ bias, ushort* __restrict__ tb,
                                               float* __restrict__ stats) {
    __shared__ ushort xt[64][40];     // cols 0..18 data, 19..31 zero, 32..39 pad
    __shared__ float red[4][128];
    int t = threadIdx.x, rb = blockIdx.x;
    int row0 = rb * 64;
    int nv = min(64, NODES - row0);
    unsigned* xz = (unsigned*)xt;
    for (int i = t; i < 64 * 20; i += TPB) xz[i] = 0;
    __syncthreads();
    const float* xs = x + (size_t)row0 * DIN;
    for (int e = t; e < nv * DIN; e += TPB) {
        int n = e / DIN, k = e - n * DIN;
        xt[n][k] = bf16bits(xs[e]);
    }
    __syncthreads();
    int lane = t & 63, wave = t >> 6;
    int r = lane & 15, g = lane >> 4;
    f32x4 acc[4] = {{0.f,0.f,0.f,0.f},{0.f,0.f,0.f,0.f},{0.f,0.f,0.f,0.f},{0.f,0.f,0.f,0.f}};
    s16x8 af = *(const s16x8*)&xt[wave * 16 + r][g * 8];
    #pragma unroll
    for (int j = 0; j < 4; ++j) {
        s16x8 bf = *(const s16x8*)(WiT + (size_t)(j * 16 + r) * 32 + g * 8);
        acc[j] = __builtin_amdgcn_mfma_f32_16x16x32_bf16(af, bf, acc[j], 0, 0, 0);
    }
    gemm_epilogue(t, row0, acc, bias, tb, stats, red);
}

// ---------------- fused layer kernel: mean-agg 64 rows -> LDS, GEMM [agg|h] @ Wcat ----------------

__global__ __launch_bounds__(TPB) void k_aggemm(const int* __restrict__ off, const int* __restrict__ ebuf,
                                                const float* __restrict__ rden, const ushort* __restrict__ hb,
                                                const ushort* __restrict__ WT, const float* __restrict__ bias,
                                                ushort* __restrict__ tb, float* __restrict__ stats) {
    __shared__ ushort aggt[64][136];
    __shared__ float red[4][128];
    int t = threadIdx.x, rb = blockIdx.x;
    const unsigned* HB = (const unsigned*)hb;            // 32 uints per row
    unsigned (*AG)[68] = (unsigned (*)[68])aggt;
    int lane = t & 63, wave = t >> 6;
    int half = lane >> 5, fl = lane & 31;
    #pragma unroll 1
    for (int i = 0; i < 16; ++i) {
        int n = rb * 64 + wave * 16 + i;
        if (n < NODES) {
            int p0 = off[n], p1 = off[n + 1];
            float a0 = 0.0f, a1 = 0.0f;
            int p = p0 + half;
            for (; p + 6 < p1; p += 8) {
                int s0 = ebuf[p], s1 = ebuf[p + 2], s2 = ebuf[p + 4], s3 = ebuf[p + 6];
                unsigned v0 = HB[(size_t)s0 * 32 + fl];
                unsigned v1 = HB[(size_t)s1 * 32 + fl];
                unsigned v2 = HB[(size_t)s2 * 32 + fl];
                unsigned v3 = HB[(size_t)s3 * 32 + fl];
                a0 += bf16lo(v0); a1 += bf16hi(v0);
                a0 += bf16lo(v1); a1 += bf16hi(v1);
                a0 += bf16lo(v2); a1 += bf16hi(v2);
                a0 += bf16lo(v3); a1 += bf16hi(v3);
            }
            for (; p < p1; p += 2) {
                unsigned v = HB[(size_t)ebuf[p] * 32 + fl];
                a0 += bf16lo(v); a1 += bf16hi(v);
            }
            a0 += __shfl_xor(a0, 32);
            a1 += __shfl_xor(a1, 32);
            if (half == 0) {
                float rd = rden[n];
                AG[wave * 16 + i][fl] =
                    (unsigned)bf16bits(a0 * rd) | ((unsigned)bf16bits(a1 * rd) << 16);
            }
        }
    }
    __syncthreads();
    int r = lane & 15, g = lane >> 4;
    int row0 = rb * 64;
    int ar = row0 + wave * 16 + r;
    if (ar >= NODES) ar = NODES - 1;
    f32x4 acc[4] = {{0.f,0.f,0.f,0.f},{0.f,0.f,0.f,0.f},{0.f,0.f,0.f,0.f},{0.f,0.f,0.f,0.f}};
    #pragma unroll
    for (int k0 = 0; k0 < 128; k0 += 32) {
        s16x8 af;
        if (k0 < 64) af = *(const s16x8*)&aggt[wave * 16 + r][k0 + g * 8];
        else         af = *(const s16x8*)(hb + (size_t)ar * 64 + (k0 - 64) + g * 8);
        #pragma unroll
        for (int j = 0; j < 4; ++j) {
            s16x8 bf = *(const s16x8*)(WT + (size_t)(j * 16 + r) * 128 + k0 + g * 8);
            acc[j] = __builtin_amdgcn_mfma_f32_16x16x32_bf16(af, bf, acc[j], 0, 0, 0);
        }
    }
    gemm_epilogue(t, row0, acc, bias, tb, stats, red);
}

// ---------------- BN finalize + ReLU (+residual) ----------------

__global__ void k_apply(const ushort* __restrict__ tb, const float* __restrict__ stats,
                        const float* __restrict__ gamma, const float* __restrict__ beta,
                        float* __restrict__ h, ushort* __restrict__ hb,
                        int residual, int write_hb) {
    int idx0 = blockIdx.x * blockDim.x + threadIdx.x;
    int stride = gridDim.x * blockDim.x;
    const float invN = 1.0f / NODES;
    for (int idx = idx0; idx < NODES * 16; idx += stride) {
        int n = idx >> 4;
        int j = (idx & 15) * 4;
        ushort4 tv = *(const ushort4*)(tb + (size_t)n * 64 + j);
        float tf[4] = { __uint_as_float((unsigned)tv.x << 16), __uint_as_float((unsigned)tv.y << 16),
                        __uint_as_float((unsigned)tv.z << 16), __uint_as_float((unsigned)tv.w << 16) };
        f32x4 hv;
        if (residual) hv = *(const f32x4*)(h + (size_t)n * 64 + j);
        float out[4];
        ushort ub[4];
        #pragma unroll
        for (int k = 0; k < 4; ++k) {
            int f = j + k;
            float mu = stats[f * 16] * invN;
            float var = stats[(64 + f) * 16] * invN - mu * mu;
            float sc = gamma[f] * rsqrtf(var + BN_EPS);
            float sh = beta[f] - mu * sc;
            float v = fmaxf(tf[k] * sc + sh, 0.0f);
            out[k] = residual ? (hv[k] + v) : v;
            ub[k] = bf16bits(out[k]);
        }
        *(f32x4*)(h + (size_t)n * 64 + j) = f32x4{out[0], out[1], out[2], out[3]};
        if (write_hb)
            *(ushort4*)(hb + (size_t)n * 64 + j) = make_ushort4(ub[0], ub[1], ub[2], ub[3]);
    }
}

// ---------------- launch ----------------

extern "C" void kernel_launch(void* const* d_in, const int* in_sizes, int n_in,
                              void* d_out, int out_size, void* d_ws, size_t ws_size,
                              hipStream_t stream) {
    const float* x    = (const float*)d_in[0];
    const int*   ei   = (const int*)d_in[1];
    const float* w_in = (const float*)d_in[2];
    const float* b_in = (const float*)d_in[3];
    const float* bn0g = (const float*)d_in[4];
    const float* bn0b = (const float*)d_in[5];
    const float* wl   = (const float*)d_in[6];
    const float* bl   = (const float*)d_in[7];
    const float* wr   = (const float*)d_in[8];
    const float* bng  = (const float*)d_in[9];
    const float* bnb  = (const float*)d_in[10];
    const int* esrc = ei;
    const int* edst = ei + EDGES;
    float* h = (float*)d_out;

    char* p = (char*)d_ws;
    auto alloc = [&](size_t bytes) {
        char* r = p;
        p += (bytes + 255) & ~size_t(255);
        return r;
    };
    int*      bintot = (int*)alloc((size_t)NBINS * 4);
    float*    stats  = (float*)alloc((size_t)4 * 2048 * 4);
    int2*     cb     = (int2*)alloc((size_t)NBINS * NBLK * 8);
    unsigned* bbuf   = (unsigned*)alloc((size_t)NBLK * EPB * 4);
    int*      off    = (int*)alloc((size_t)(NODES + 1) * 4);
    float*    rden   = (float*)alloc((size_t)NODES * 4);
    int*      ebuf   = (int*)alloc((size_t)EDGES * 4);
    ushort*   WiT    = (ushort*)alloc(64 * 32 * 2);
    ushort*   WcatT  = (ushort*)alloc(LAYERS * 64 * 128 * 2);
    ushort*   tb     = (ushort*)alloc((size_t)NODES * 64 * 2);
    ushort*   hb     = (ushort*)alloc((size_t)NODES * 64 * 2);

    k_wprep<<<128, TPB, 0, stream>>>(w_in, wl, wr, WiT, WcatT, bintot, stats);
    k_sortA<<<NBLK, 1024, 0, stream>>>(esrc, edst, cb, bintot, bbuf);
    k_binB<<<NBINS, TPB, 0, stream>>>(cb, bintot, bbuf, off, rden, ebuf);

    k_gemm0<<<NTILES, TPB, 0, stream>>>(x, WiT, b_in, tb, stats);
    k_apply<<<2048, TPB, 0, stream>>>(tb, stats, bn0g, bn0b, h, hb, 0, 1);

    for (int l = 0; l < LAYERS; ++l) {
        k_aggemm<<<NTILES, TPB, 0, stream>>>(off, ebuf, rden, hb, WcatT + l * 8192,
                                             bl + l * 64, tb, stats + (l + 1) * 2048);
        k_apply<<<2048, TPB, 0, stream>>>(tb, stats + (l + 1) * 2048, bng + l * 64, bnb + l * 64,
                                          h, hb, 1, l < LAYERS - 1 ? 1 : 0);
    }
}

// Round 8
// 295.246 us; speedup vs baseline: 2.3145x; 1.2220x over previous
//
#include <hip/hip_runtime.h>
#include <hip/hip_bf16.h>

#define NODES 50000
#define EDGES 800000
#define DIN   19
#define LAYERS 3
#define BN_EPS 1e-5f

#define NBINS 196          // ceil(NODES/256), bin = dst>>8
#define EPB   4096         // edges per sort chunk
#define NBLK  196          // ceil(EDGES/EPB)
#define NTILES 782         // ceil(NODES/64)
#define TPB   256

typedef __attribute__((ext_vector_type(4))) float f32x4;
typedef __attribute__((ext_vector_type(2))) float f32x2;
typedef __attribute__((ext_vector_type(8))) short s16x8;

__device__ inline ushort bf16bits(float f) {
    __hip_bfloat16 h = __float2bfloat16(f);
    return *reinterpret_cast<ushort*>(&h);
}

// ---------- fp8 pack/unpack (e4m3 via HW cvt; e5m2-from-f16 fallback, header-free) ----------
#if __has_builtin(__builtin_amdgcn_cvt_pk_f32_fp8) && __has_builtin(__builtin_amdgcn_cvt_pk_fp8_f32)
__device__ inline unsigned pack4_fp8(float a, float b, float c, float d) {
    unsigned w = __builtin_amdgcn_cvt_pk_fp8_f32(a, b, 0u, false);
    return __builtin_amdgcn_cvt_pk_fp8_f32(c, d, w, true);
}
__device__ inline void acc4_fp8(unsigned v, float& a0, float& a1, float& a2, float& a3) {
    f32x2 lo = __builtin_amdgcn_cvt_pk_f32_fp8(v, false);
    f32x2 hi = __builtin_amdgcn_cvt_pk_f32_fp8(v, true);
    a0 += lo.x; a1 += lo.y; a2 += hi.x; a3 += hi.y;
}
#else
__device__ inline unsigned enc1(float f) {            // e5m2 = top byte of fp16, RN
    _Float16 hf = (_Float16)f;
    unsigned u = (unsigned)*reinterpret_cast<unsigned short*>(&hf);
    u = (u + 0x7Fu + ((u >> 8) & 1u)) >> 8;
    return u & 0xFFu;
}
__device__ inline float dec1(unsigned b) {
    unsigned short u = (unsigned short)(b << 8);
    _Float16 hf = *reinterpret_cast<_Float16*>(&u);
    return (float)hf;
}
__device__ inline unsigned pack4_fp8(float a, float b, float c, float d) {
    return enc1(a) | (enc1(b) << 8) | (enc1(c) << 16) | (enc1(d) << 24);
}
__device__ inline void acc4_fp8(unsigned v, float& a0, float& a1, float& a2, float& a3) {
    a0 += dec1(v & 0xFF); a1 += dec1((v >> 8) & 0xFF);
    a2 += dec1((v >> 16) & 0xFF); a3 += dec1(v >> 24);
}
#endif

// ---------------- prep: zero counters/stats, build transposed bf16 weights ----------------

__global__ void k_wprep(const float* __restrict__ w_in, const float* __restrict__ wl,
                        const float* __restrict__ wr, ushort* __restrict__ WiT,
                        ushort* __restrict__ WcatT, int* __restrict__ bintot,
                        float* __restrict__ stats) {
    int i0 = blockIdx.x * blockDim.x + threadIdx.x;
    int stride = gridDim.x * blockDim.x;
    for (int i = i0; i < NBINS; i += stride) bintot[i] = 0;
    for (int i = i0; i < 4 * 2048; i += stride) stats[i] = 0.0f;
    for (int i = i0; i < 64 * 32; i += stride) {
        int c = i >> 5, k = i & 31;
        WiT[i] = bf16bits(k < DIN ? w_in[k * 64 + c] : 0.0f);
    }
    for (int i = i0; i < LAYERS * 64 * 128; i += stride) {
        int l = i >> 13, rem = i & 8191;
        int c = rem >> 7, k = rem & 127;
        float v = (k < 64) ? wl[(l * 64 + k) * 64 + c] : wr[(l * 64 + (k - 64)) * 64 + c];
        WcatT[i] = bf16bits(v);
    }
}

// ---------------- pass A: per-block LDS counting sort of edges by dst>>8 ----------------

__global__ __launch_bounds__(1024) void k_sortA(const int* __restrict__ src, const int* __restrict__ dst,
                                                int2* __restrict__ cb, int* __restrict__ bintot,
                                                unsigned* __restrict__ bbuf) {
    __shared__ int hist[256];
    __shared__ int cur[256];
    __shared__ int wsum4[4];
    __shared__ unsigned stage[EPB];
    int blk = blockIdx.x, t = threadIdx.x;
    int e0 = blk * EPB;
    int ne = min(EPB, EDGES - e0);
    int d[4]; unsigned pk[4];
    #pragma unroll
    for (int i = 0; i < 4; ++i) {
        int j = t + i * 1024;
        if (j < ne) {
            int dd = dst[e0 + j];
            d[i] = dd;
            pk[i] = ((unsigned)(dd & 255) << 24) | (unsigned)src[e0 + j];
        } else d[i] = -1;
    }
    if (t < 256) hist[t] = 0;
    __syncthreads();
    #pragma unroll
    for (int i = 0; i < 4; ++i)
        if (d[i] >= 0) atomicAdd(&hist[d[i] >> 8], 1);
    __syncthreads();
    int ln = t & 63, wv = t >> 6;
    int cntv = 0, inc = 0;
    if (t < 256) {
        cntv = hist[t];
        inc = cntv;
        #pragma unroll
        for (int s = 1; s < 64; s <<= 1) {
            int u = __shfl_up(inc, s);
            if (ln >= s) inc += u;
        }
        if (ln == 63) wsum4[wv] = inc;
    }
    __syncthreads();
    if (t < 256) {
        int woff = 0;
        #pragma unroll
        for (int i = 0; i < 4; ++i) if (i < wv) woff += wsum4[i];
        int excl = woff + inc - cntv;
        cur[t] = excl;
        if (t < NBINS) {
            cb[t * NBLK + blk] = make_int2(excl, cntv);
            if (cntv) atomicAdd(&bintot[t], cntv);
        }
    }
    __syncthreads();
    #pragma unroll
    for (int i = 0; i < 4; ++i)
        if (d[i] >= 0) {
            int slot = atomicAdd(&cur[d[i] >> 8], 1);
            stage[slot] = pk[i];
        }
    __syncthreads();
    #pragma unroll
    for (int i = 0; i < 4; ++i) {
        int j = t + i * 1024;
        if (j < ne) bbuf[e0 + j] = stage[j];
    }
}

// ---------------- pass B: per-bin CSR assembly (flattened edge iteration) ----------------

__device__ inline int ubound(const int* pre, int f) {
    int lo = 0, hi = NBLK;
    while (lo + 1 < hi) {
        int mid = (lo + hi) >> 1;
        if (pre[mid] <= f) lo = mid; else hi = mid;
    }
    return lo;
}

__global__ __launch_bounds__(TPB) void k_binB(const int2* __restrict__ cb, const int* __restrict__ bintot,
                                              const unsigned* __restrict__ bbuf,
                                              int* __restrict__ off, float* __restrict__ rden,
                                              int* __restrict__ ebuf) {
    __shared__ int red[256];
    __shared__ int segoff[NBLK], segcnt[NBLK], pre[NBLK + 1];
    __shared__ int deg[256], loff[256], cur[256];
    __shared__ int wsum4[4];
    int b = blockIdx.x, t = threadIdx.x;
    int ln = t & 63, wv = t >> 6;
    red[t] = (t < b) ? bintot[t] : 0;
    __syncthreads();
    #pragma unroll
    for (int s = 128; s > 0; s >>= 1) {
        if (t < s) red[t] += red[t + s];
        __syncthreads();
    }
    int binoff = red[0];
    if (t < NBLK) {
        int2 c = cb[b * NBLK + t];
        segoff[t] = c.x; segcnt[t] = c.y;
    }
    deg[t] = 0; cur[t] = 0;
    __syncthreads();
    if (wv == 0) {
        int carry = 0;
        for (int base = 0; base < NBLK; base += 64) {
            int idx = base + ln;
            int v = (idx < NBLK) ? segcnt[idx] : 0;
            int inc = v;
            #pragma unroll
            for (int s = 1; s < 64; s <<= 1) {
                int u = __shfl_up(inc, s);
                if (ln >= s) inc += u;
            }
            if (idx < NBLK) pre[idx] = carry + inc - v;
            carry += __shfl(inc, 63);
        }
        if (ln == 0) pre[NBLK] = carry;
    }
    __syncthreads();
    int total = pre[NBLK];
    for (int f = t; f < total; f += TPB) {
        int sg = ubound(pre, f);
        unsigned e = bbuf[sg * EPB + segoff[sg] + (f - pre[sg])];
        atomicAdd(&deg[e >> 24], 1);
    }
    __syncthreads();
    int dv = deg[t], inc2 = dv;
    #pragma unroll
    for (int s = 1; s < 64; s <<= 1) {
        int u = __shfl_up(inc2, s);
        if (ln >= s) inc2 += u;
    }
    if (ln == 63) wsum4[wv] = inc2;
    __syncthreads();
    int woff = 0;
    #pragma unroll
    for (int i = 0; i < 4; ++i) if (i < wv) woff += wsum4[i];
    int excl = woff + inc2 - dv;
    loff[t] = excl;
    int node = (b << 8) + t;
    if (node < NODES) {
        off[node] = binoff + excl;
        rden[node] = 1.0f / fmaxf((float)dv, 1.0f);
    }
    if (b == NBINS - 1 && t == 0) off[NODES] = EDGES;
    __syncthreads();
    for (int f = t; f < total; f += TPB) {
        int sg = ubound(pre, f);
        unsigned e = bbuf[sg * EPB + segoff[sg] + (f - pre[sg])];
        int dd = e >> 24;
        int slot = atomicAdd(&cur[dd], 1);
        ebuf[binoff + loff[dd] + slot] = (int)(e & 0xFFFFFFu);
    }
}

// ---------------- shared GEMM epilogue: bias + bf16 store + fused BN stats ----------------

__device__ inline void gemm_epilogue(int t, int row0, f32x4* acc, const float* __restrict__ bias,
                                     ushort* __restrict__ tb, float* __restrict__ stats,
                                     float (*red)[128]) {
    int lane = t & 63, wave = t >> 6;
    int r = lane & 15, g = lane >> 4;
    float s_[4], q_[4];
    #pragma unroll
    for (int j = 0; j < 4; ++j) {
        float b = bias[j * 16 + r];
        float s = 0.0f, q = 0.0f;
        #pragma unroll
        for (int i = 0; i < 4; ++i) {
            int row = row0 + wave * 16 + g * 4 + i;
            if (row < NODES) {
                float v = acc[j][i] + b;
                tb[(size_t)row * 64 + j * 16 + r] = bf16bits(v);
                s += v; q += v * v;
            }
        }
        s += __shfl_xor(s, 16); s += __shfl_xor(s, 32);
        q += __shfl_xor(q, 16); q += __shfl_xor(q, 32);
        s_[j] = s; q_[j] = q;
    }
    if (g == 0) {
        #pragma unroll
        for (int j = 0; j < 4; ++j) {
            red[wave][j * 16 + r] = s_[j];
            red[wave][64 + j * 16 + r] = q_[j];
        }
    }
    __syncthreads();
    if (t < 128) {
        float tot = red[0][t] + red[1][t] + red[2][t] + red[3][t];
        atomicAdd(&stats[t * 16], tot);
    }
}

// ---------------- input-proj GEMM: stages x (fp32) -> bf16 LDS tile, K=32 ----------------

__global__ __launch_bounds__(TPB) void k_gemm0(const float* __restrict__ x, const ushort* __restrict__ WiT,
                                               const float* __restrict__ bias, ushort* __restrict__ tb,
                                               float* __restrict__ stats) {
    __shared__ ushort xt[64][40];
    __shared__ float red[4][128];
    int t = threadIdx.x, rb = blockIdx.x;
    int row0 = rb * 64;
    int nv = min(64, NODES - row0);
    unsigned* xz = (unsigned*)xt;
    for (int i = t; i < 64 * 20; i += TPB) xz[i] = 0;
    __syncthreads();
    const float* xs = x + (size_t)row0 * DIN;
    for (int e = t; e < nv * DIN; e += TPB) {
        int n = e / DIN, k = e - n * DIN;
        xt[n][k] = bf16bits(xs[e]);
    }
    __syncthreads();
    int lane = t & 63, wave = t >> 6;
    int r = lane & 15, g = lane >> 4;
    f32x4 acc[4] = {{0.f,0.f,0.f,0.f},{0.f,0.f,0.f,0.f},{0.f,0.f,0.f,0.f},{0.f,0.f,0.f,0.f}};
    s16x8 af = *(const s16x8*)&xt[wave * 16 + r][g * 8];
    #pragma unroll
    for (int j = 0; j < 4; ++j) {
        s16x8 bf = *(const s16x8*)(WiT + (size_t)(j * 16 + r) * 32 + g * 8);
        acc[j] = __builtin_amdgcn_mfma_f32_16x16x32_bf16(af, bf, acc[j], 0, 0, 0);
    }
    gemm_epilogue(t, row0, acc, bias, tb, stats, red);
}

// ---------------- layer GEMM: A = AB[n][128] ([agg|h] bf16), W = WcatT ----------------

__global__ __launch_bounds__(TPB) void k_gemm(const ushort* __restrict__ AB, const ushort* __restrict__ WT,
                                              const float* __restrict__ bias, ushort* __restrict__ tb,
                                              float* __restrict__ stats) {
    __shared__ float red[4][128];
    int t = threadIdx.x;
    int lane = t & 63, wave = t >> 6;
    int row0 = blockIdx.x * 64;
    int r = lane & 15, g = lane >> 4;
    f32x4 acc[4] = {{0.f,0.f,0.f,0.f},{0.f,0.f,0.f,0.f},{0.f,0.f,0.f,0.f},{0.f,0.f,0.f,0.f}};
    int ar = row0 + wave * 16 + r;
    if (ar >= NODES) ar = NODES - 1;
    #pragma unroll
    for (int k0 = 0; k0 < 128; k0 += 32) {
        s16x8 af = *(const s16x8*)(AB + (size_t)ar * 128 + k0 + g * 8);
        #pragma unroll
        for (int j = 0; j < 4; ++j) {
            s16x8 bf = *(const s16x8*)(WT + (size_t)(j * 16 + r) * 128 + k0 + g * 8);
            acc[j] = __builtin_amdgcn_mfma_f32_16x16x32_bf16(af, bf, acc[j], 0, 0, 0);
        }
    }
    gemm_epilogue(t, row0, acc, bias, tb, stats, red);
}

// ---------------- BN finalize + ReLU (+residual); writes h, AB right half, fp8 table ----------------

__global__ void k_apply(const ushort* __restrict__ tb, const float* __restrict__ stats,
                        const float* __restrict__ gamma, const float* __restrict__ beta,
                        float* __restrict__ h, ushort* __restrict__ AB,
                        unsigned* __restrict__ hb8, int residual, int write_next) {
    int idx0 = blockIdx.x * blockDim.x + threadIdx.x;
    int stride = gridDim.x * blockDim.x;
    const float invN = 1.0f / NODES;
    for (int idx = idx0; idx < NODES * 16; idx += stride) {
        int n = idx >> 4;
        int j = (idx & 15) * 4;
        ushort4 tv = *(const ushort4*)(tb + (size_t)n * 64 + j);
        float tf[4] = { __uint_as_float((unsigned)tv.x << 16), __uint_as_float((unsigned)tv.y << 16),
                        __uint_as_float((unsigned)tv.z << 16), __uint_as_float((unsigned)tv.w << 16) };
        f32x4 hv;
        if (residual) hv = *(const f32x4*)(h + (size_t)n * 64 + j);
        float out[4];
        ushort ub[4];
        #pragma unroll
        for (int k = 0; k < 4; ++k) {
            int f = j + k;
            float mu = stats[f * 16] * invN;
            float var = stats[(64 + f) * 16] * invN - mu * mu;
            float sc = gamma[f] * rsqrtf(var + BN_EPS);
            float sh = beta[f] - mu * sc;
            float v = fmaxf(tf[k] * sc + sh, 0.0f);
            out[k] = residual ? (hv[k] + v) : v;
            ub[k] = bf16bits(out[k]);
        }
        *(f32x4*)(h + (size_t)n * 64 + j) = f32x4{out[0], out[1], out[2], out[3]};
        if (write_next) {
            *(ushort4*)(AB + (size_t)n * 128 + 64 + j) = make_ushort4(ub[0], ub[1], ub[2], ub[3]);
            hb8[(size_t)n * 16 + (idx & 15)] = pack4_fp8(out[0], out[1], out[2], out[3]);
        }
    }
}

// ---------------- mean aggregation: fp8 gathers, 4 edges/wave x 4-unroll ----------------

__global__ void k_agg(const int* __restrict__ off, const int* __restrict__ ebuf,
                      const float* __restrict__ rden, const unsigned* __restrict__ hb8,
                      ushort* __restrict__ ABh) {
    unsigned* AB = (unsigned*)ABh;          // rows = 64 uints (2 bf16 each)
    int t = threadIdx.x;
    int lane = t & 63;
    int q = lane >> 4;                      // edge slot 0..3
    int fl = lane & 15;                     // feature-word (4 features)
    int w = blockIdx.x * (blockDim.x >> 6) + (t >> 6);
    int nw = gridDim.x * (blockDim.x >> 6);
    for (int n = w; n < NODES; n += nw) {
        int p0 = off[n], p1 = off[n + 1];
        float a0 = 0.f, a1 = 0.f, a2 = 0.f, a3 = 0.f;
        int p = p0 + q;
        for (; p + 12 < p1; p += 16) {
            int s0 = ebuf[p], s1 = ebuf[p + 4], s2 = ebuf[p + 8], s3 = ebuf[p + 12];
            unsigned v0 = hb8[(size_t)s0 * 16 + fl];
            unsigned v1 = hb8[(size_t)s1 * 16 + fl];
            unsigned v2 = hb8[(size_t)s2 * 16 + fl];
            unsigned v3 = hb8[(size_t)s3 * 16 + fl];
            acc4_fp8(v0, a0, a1, a2, a3);
            acc4_fp8(v1, a0, a1, a2, a3);
            acc4_fp8(v2, a0, a1, a2, a3);
            acc4_fp8(v3, a0, a1, a2, a3);
        }
        for (; p < p1; p += 4) {
            unsigned v = hb8[(size_t)ebuf[p] * 16 + fl];
            acc4_fp8(v, a0, a1, a2, a3);
        }
        a0 += __shfl_xor(a0, 16); a0 += __shfl_xor(a0, 32);
        a1 += __shfl_xor(a1, 16); a1 += __shfl_xor(a1, 32);
        a2 += __shfl_xor(a2, 16); a2 += __shfl_xor(a2, 32);
        a3 += __shfl_xor(a3, 16); a3 += __shfl_xor(a3, 32);
        if (q == 0) {
            float rd = rden[n];
            uint2 o;
            o.x = (unsigned)bf16bits(a0 * rd) | ((unsigned)bf16bits(a1 * rd) << 16);
            o.y = (unsigned)bf16bits(a2 * rd) | ((unsigned)bf16bits(a3 * rd) << 16);
            *(uint2*)(AB + (size_t)n * 64 + fl * 2) = o;
        }
    }
}

// ---------------- launch ----------------

extern "C" void kernel_launch(void* const* d_in, const int* in_sizes, int n_in,
                              void* d_out, int out_size, void* d_ws, size_t ws_size,
                              hipStream_t stream) {
    const float* x    = (const float*)d_in[0];
    const int*   ei   = (const int*)d_in[1];
    const float* w_in = (const float*)d_in[2];
    const float* b_in = (const float*)d_in[3];
    const float* bn0g = (const float*)d_in[4];
    const float* bn0b = (const float*)d_in[5];
    const float* wl   = (const float*)d_in[6];
    const float* bl   = (const float*)d_in[7];
    const float* wr   = (const float*)d_in[8];
    const float* bng  = (const float*)d_in[9];
    const float* bnb  = (const float*)d_in[10];
    const int* esrc = ei;
    const int* edst = ei + EDGES;
    float* h = (float*)d_out;

    char* p = (char*)d_ws;
    auto alloc = [&](size_t bytes) {
        char* r = p;
        p += (bytes + 255) & ~size_t(255);
        return r;
    };
    int*      bintot = (int*)alloc((size_t)NBINS * 4);
    float*    stats  = (float*)alloc((size_t)4 * 2048 * 4);
    int2*     cb     = (int2*)alloc((size_t)NBINS * NBLK * 8);
    unsigned* bbuf   = (unsigned*)alloc((size_t)NBLK * EPB * 4);
    int*      off    = (int*)alloc((size_t)(NODES + 1) * 4);
    float*    rden   = (float*)alloc((size_t)NODES * 4);
    int*      ebuf   = (int*)alloc((size_t)EDGES * 4);
    ushort*   WiT    = (ushort*)alloc(64 * 32 * 2);
    ushort*   WcatT  = (ushort*)alloc(LAYERS * 64 * 128 * 2);
    ushort*   tb     = (ushort*)alloc((size_t)NODES * 64 * 2);
    ushort*   AB     = (ushort*)alloc((size_t)NODES * 128 * 2);
    unsigned* hb8    = (unsigned*)alloc((size_t)NODES * 16 * 4);

    k_wprep<<<128, TPB, 0, stream>>>(w_in, wl, wr, WiT, WcatT, bintot, stats);
    k_sortA<<<NBLK, 1024, 0, stream>>>(esrc, edst, cb, bintot, bbuf);
    k_binB<<<NBINS, TPB, 0, stream>>>(cb, bintot, bbuf, off, rden, ebuf);

    k_gemm0<<<NTILES, TPB, 0, stream>>>(x, WiT, b_in, tb, stats);
    k_apply<<<2048, TPB, 0, stream>>>(tb, stats, bn0g, bn0b, h, AB, hb8, 0, 1);

    for (int l = 0; l < LAYERS; ++l) {
        k_agg<<<2048, TPB, 0, stream>>>(off, ebuf, rden, hb8, AB);
        k_gemm<<<NTILES, TPB, 0, stream>>>(AB, WcatT + l * 8192, bl + l * 64,
                                           tb, stats + (l + 1) * 2048);
        k_apply<<<2048, TPB, 0, stream>>>(tb, stats + (l + 1) * 2048, bng + l * 64, bnb + l * 64,
                                          h, AB, hb8, 1, l < LAYERS - 1 ? 1 : 0);
    }
}